// Round 7
// baseline (68.741 us; speedup 1.0000x reference)
//
#include <hip/hip_runtime.h>
#include <hip/hip_bf16.h>

#define KK 32
#define DD 512
#define BB 16
#define NN 4096

typedef __attribute__((ext_vector_type(8))) short short8;
typedef __attribute__((ext_vector_type(4))) float f32x4;

__device__ __forceinline__ unsigned short f2bf(float f) {
    unsigned u = __builtin_bit_cast(unsigned, f);
    u += 0x7fffu + ((u >> 16) & 1u);   // RNE bf16
    return (unsigned short)(u >> 16);
}

// ---------------- kernel 0: c2[k], s2[k], codes->bf16 ----------------
__global__ __launch_bounds__(256) void k_prep(const float* __restrict__ codes,
                                              const float* __restrict__ scale,
                                              float* __restrict__ c2w,
                                              float* __restrict__ s2w,
                                              unsigned short* __restrict__ codesb) {
    __shared__ float red[KK][8];
    int tid = threadIdx.x;
    int k = tid >> 3, pt = tid & 7;
    const float4* p = reinterpret_cast<const float4*>(codes + k * DD + pt * 64);
    ushort4* cb = reinterpret_cast<ushort4*>(codesb + k * DD + pt * 64);
    float s = 0.f;
#pragma unroll
    for (int i = 0; i < 16; ++i) {
        float4 v = p[i];
        s += v.x * v.x + v.y * v.y + v.z * v.z + v.w * v.w;
        ushort4 h;
        h.x = f2bf(v.x); h.y = f2bf(v.y); h.z = f2bf(v.z); h.w = f2bf(v.w);
        cb[i] = h;
    }
    red[k][pt] = s;
    __syncthreads();
    if (tid < KK) {
        float c2 = 0.f;
#pragma unroll
        for (int j = 0; j < 8; ++j) c2 += red[tid][j];
        c2w[tid] = c2;
        float sc = scale[tid];
        s2w[tid] = sc * sc;
    }
}

// ---------------- pass A: softmax assignments (barrier-free main loop) ----------------
// 256 threads = 4 waves; each wave owns 16 tokens end-to-end (private 2x1KB LDS tile).
// grid = 16 b * 64 chunks = 1024 (4 blocks/CU).
__global__ __launch_bounds__(256) void k_assign(const float* __restrict__ x,
                                                const unsigned short* __restrict__ codesb,
                                                const float* __restrict__ c2w,
                                                const float* __restrict__ s2w,
                                                unsigned short* __restrict__ Aout,
                                                float* __restrict__ sAp) {
    __shared__ unsigned short xt[4][2][32 * 16];   // per-wave double-buffered [d32][tok16]
    __shared__ float x2w[4][16];
    __shared__ float sA_lds[4][32];

    int tid = threadIdx.x;
    int lane = tid & 63;
    int w = tid >> 6;
    int g = lane >> 4, c = lane & 15;
    int bid = blockIdx.x;
    int b = bid >> 6;
    int chunk = bid & 63;
    int tok0 = (chunk << 6) + (w << 4);    // this wave's 16 tokens

    int lr = lane >> 1;                    // row 0..31 within the 32-d tile slice
    int lh = lane & 1;                     // token octet 0/1
    const float* xb = x + (size_t)b * DD * NN + tok0 + lh * 8;
    char* wt = reinterpret_cast<char*>(&xt[w][0][0]);

    float s2k0 = s2w[c], s2k1 = s2w[c + 16];
    float c2k0 = c2w[c], c2k1 = c2w[c + 16];

    f32x4 acc0 = {}, acc1 = {};
    float x2p[8] = {0.f, 0.f, 0.f, 0.f, 0.f, 0.f, 0.f, 0.f};

    int wbyte = ((lr << 5) + (lh << 4)) ^ (((lr >> 3) & 3) << 5);

#pragma unroll
    for (int it = 0; it < 16; ++it) {
        // load 1 d-row x 8 tokens (32 B contiguous) for this iteration's tile slice
        const float* pr = xb + (size_t)(it * 32 + lr) * NN;
        float4 v0 = *reinterpret_cast<const float4*>(pr);
        float4 v1 = *reinterpret_cast<const float4*>(pr + 4);
        x2p[0] += v0.x * v0.x; x2p[1] += v0.y * v0.y;
        x2p[2] += v0.z * v0.z; x2p[3] += v0.w * v0.w;
        x2p[4] += v1.x * v1.x; x2p[5] += v1.y * v1.y;
        x2p[6] += v1.z * v1.z; x2p[7] += v1.w * v1.w;
        short8 h;
        h[0] = (short)f2bf(v0.x); h[1] = (short)f2bf(v0.y);
        h[2] = (short)f2bf(v0.z); h[3] = (short)f2bf(v0.w);
        h[4] = (short)f2bf(v1.x); h[5] = (short)f2bf(v1.y);
        h[6] = (short)f2bf(v1.z); h[7] = (short)f2bf(v1.w);
        char* bufp = wt + ((it & 1) << 10);
        *reinterpret_cast<short8*>(bufp + wbyte) = h;

        // A-frag: token col c, d rows g*8+j (wave-internal lgkmcnt ordering, no barrier)
        short8 af;
#pragma unroll
        for (int j = 0; j < 8; ++j) {
            int row = g * 8 + j;
            af[j] = *reinterpret_cast<const short*>(
                bufp + (((row << 5) + (c << 1)) ^ ((g & 3) << 5)));
        }
        short8 b0 = *reinterpret_cast<const short8*>(codesb + (c << 9) + it * 32 + (g << 3));
        short8 b1 = *reinterpret_cast<const short8*>(codesb + ((c + 16) << 9) + it * 32 + (g << 3));
        acc0 = __builtin_amdgcn_mfma_f32_16x16x32_bf16(af, b0, acc0, 0, 0, 0);
        acc1 = __builtin_amdgcn_mfma_f32_16x16x32_bf16(af, b1, acc1, 0, 0, 0);
    }

    // x2 per token: reduce over rows (lanes with same lane&1), exact fp32
#pragma unroll
    for (int q = 0; q < 8; ++q) {
        x2p[q] += __shfl_xor(x2p[q], 2);
        x2p[q] += __shfl_xor(x2p[q], 4);
        x2p[q] += __shfl_xor(x2p[q], 8);
        x2p[q] += __shfl_xor(x2p[q], 16);
        x2p[q] += __shfl_xor(x2p[q], 32);
    }
    if (lane < 2) {
#pragma unroll
        for (int q = 0; q < 8; ++q) x2w[w][lh * 8 + q] = x2p[q];
    }
    // wave-internal read-back (no barrier: same wave, lgkmcnt-ordered)
    float x2r[4];
#pragma unroll
    for (int r = 0; r < 4; ++r) x2r[r] = x2w[w][g * 4 + r];

    unsigned short* Ab = Aout + (size_t)b * NN * KK;
    float pA0 = 0.f, pA1 = 0.f;
#pragma unroll
    for (int r = 0; r < 4; ++r) {
        float d0v = s2k0 * (x2r[r] - 2.f * acc0[r] + c2k0);
        float d1v = s2k1 * (x2r[r] - 2.f * acc1[r] + c2k1);
        float m = fmaxf(d0v, d1v);
        m = fmaxf(m, __shfl_xor(m, 1));
        m = fmaxf(m, __shfl_xor(m, 2));
        m = fmaxf(m, __shfl_xor(m, 4));
        m = fmaxf(m, __shfl_xor(m, 8));
        float p0 = __expf(d0v - m), p1 = __expf(d1v - m);
        float ss = p0 + p1;
        ss += __shfl_xor(ss, 1);
        ss += __shfl_xor(ss, 2);
        ss += __shfl_xor(ss, 4);
        ss += __shfl_xor(ss, 8);
        float inv = 1.0f / ss;
        float a0 = p0 * inv, a1 = p1 * inv;
        int n = (chunk << 6) + (w << 4) + g * 4 + r;
        unsigned short* pa = Ab + ((size_t)(n >> 3) << 8) + (n & 7);   // [n/8][k=32][n%8]
        pa[c * 8] = f2bf(a0);
        pa[(c + 16) * 8] = f2bf(a1);
        pA0 += a0;
        pA1 += a1;
    }
    pA0 += __shfl_xor(pA0, 16); pA0 += __shfl_xor(pA0, 32);
    pA1 += __shfl_xor(pA1, 16); pA1 += __shfl_xor(pA1, 32);
    if (lane < 16) {
        sA_lds[w][c] = pA0;
        sA_lds[w][c + 16] = pA1;
    }
    __syncthreads();
    if (tid < 32) {
        float ss = sA_lds[0][tid] + sA_lds[1][tid] + sA_lds[2][tid] + sA_lds[3][tid];
        sAp[(b * 64 + chunk) * KK + tid] = ss;
    }
}

// ---------------- pass B: e-partials per (b, 512-tok chunk, 128-d slice) ----------------
// 512 threads (8 waves), no LDS/barriers/atomics; fp32 x, 1 d-row per lane.
// grid = 16 b * 8 nc * 4 dh = 512 (2 blocks/CU, 16 waves/CU)
__global__ __launch_bounds__(512) void k_agg(const float* __restrict__ x,
                                             const unsigned short* __restrict__ Ain,
                                             float* __restrict__ part) {
    int tid = threadIdx.x;
    int lane = tid & 63;
    int w = tid >> 6;
    int g = lane >> 4, c = lane & 15;
    int bid = blockIdx.x;
    int b = bid >> 5;
    int nc = (bid >> 2) & 7;
    int dh = bid & 3;

    int dr = dh * 128 + w * 16 + c;                       // this lane's d row
    const float* xr = x + ((size_t)b * DD + dr) * NN;
    const unsigned short* Ab = Ain + (size_t)b * NN * KK;

    f32x4 acc0 = {}, acc1 = {};
#pragma unroll 8
    for (int ns = 0; ns < 16; ++ns) {
        int n0 = nc * 512 + ns * 32 + g * 8;
        const unsigned short* pa = Ab + ((size_t)(n0 >> 3) << 8);
        short8 a0 = *reinterpret_cast<const short8*>(pa + c * 8);          // k = c
        short8 a1 = *reinterpret_cast<const short8*>(pa + c * 8 + 128);    // k = c+16
        float4 v0 = *reinterpret_cast<const float4*>(xr + n0);
        float4 v1 = *reinterpret_cast<const float4*>(xr + n0 + 4);
        short8 xf;
        xf[0] = (short)f2bf(v0.x); xf[1] = (short)f2bf(v0.y);
        xf[2] = (short)f2bf(v0.z); xf[3] = (short)f2bf(v0.w);
        xf[4] = (short)f2bf(v1.x); xf[5] = (short)f2bf(v1.y);
        xf[6] = (short)f2bf(v1.z); xf[7] = (short)f2bf(v1.w);
        acc0 = __builtin_amdgcn_mfma_f32_16x16x32_bf16(a0, xf, acc0, 0, 0, 0);
        acc1 = __builtin_amdgcn_mfma_f32_16x16x32_bf16(a1, xf, acc1, 0, 0, 0);
    }
    float* pp = part + (size_t)(b * 8 + nc) * KK * DD;
#pragma unroll
    for (int r = 0; r < 4; ++r) {
        pp[(g * 4 + r) * DD + dr] = acc0[r];
        pp[(16 + g * 4 + r) * DD + dr] = acc1[r];
    }
}

// ---------------- reduce: out = sum_{8 chunks} part - sA*codes ----------------
__global__ __launch_bounds__(256) void k_red(const float* __restrict__ part,
                                             const float* __restrict__ sAp,
                                             const float* __restrict__ codes,
                                             float* __restrict__ out) {
    int bid = blockIdx.x;        // b*32 + k
    int b = bid >> 5, k = bid & 31;
    int tid = threadIdx.x;
    int d = tid * 2;
    float sA = 0.f;
    for (int cc = 0; cc < 64; ++cc) sA += sAp[(b * 64 + cc) * KK + k];   // uniform -> s_loads
    const float* pb = part + (size_t)b * 8 * KK * DD + k * DD + d;
    float s0 = 0.f, s1 = 0.f;
#pragma unroll
    for (int cc = 0; cc < 8; ++cc) {
        float2 v = *reinterpret_cast<const float2*>(pb + (size_t)cc * KK * DD);
        s0 += v.x; s1 += v.y;
    }
    float2 cd = *reinterpret_cast<const float2*>(codes + k * DD + d);
    float2 o;
    o.x = s0 - sA * cd.x;
    o.y = s1 - sA * cd.y;
    *reinterpret_cast<float2*>(out + ((size_t)b * KK + k) * DD + d) = o;
}

extern "C" void kernel_launch(void* const* d_in, const int* in_sizes, int n_in,
                              void* d_out, int out_size, void* d_ws, size_t ws_size,
                              hipStream_t stream) {
    const float* x = (const float*)d_in[0];
    const float* codes = (const float*)d_in[1];
    const float* scale = (const float*)d_in[2];
    float* out = (float*)d_out;
    float* ws = (float*)d_ws;

    float* sAp = ws;                                          // 16*64*32 = 32768 f
    float* c2w = ws + 32768;                                  // 32
    float* s2w = ws + 32800;                                  // 32
    unsigned short* codesb = (unsigned short*)(ws + 32832);   // 32 KB bf16
    unsigned short* Abuf = (unsigned short*)(ws + 41024);     // B*N*K bf16 ~4.2 MB
    float* part = ws + 41024 + 1048576;                       // 16*8*32*512 f = 8.4 MB

    k_prep<<<1, 256, 0, stream>>>(codes, scale, c2w, s2w, codesb);
    k_assign<<<BB * 64, 256, 0, stream>>>(x, codesb, c2w, s2w, Abuf, sAp);
    k_agg<<<BB * 8 * 4, 512, 0, stream>>>(x, Abuf, part);
    k_red<<<BB * KK, 256, 0, stream>>>(part, sAp, codes, out);
}

// Round 9
// 62.557 us; speedup vs baseline: 1.0988x; 1.0988x over previous
//
#include <hip/hip_runtime.h>
#include <hip/hip_bf16.h>

#define KK 32
#define DD 512
#define BB 16
#define NN 4096

typedef __attribute__((ext_vector_type(8))) short short8;
typedef __attribute__((ext_vector_type(4))) float f32x4;

__device__ __forceinline__ unsigned short f2bf(float f) {
    unsigned u = __builtin_bit_cast(unsigned, f);
    u += 0x7fffu + ((u >> 16) & 1u);   // RNE bf16
    return (unsigned short)(u >> 16);
}
// packed bf16 pair (RNE): low = a, high = b
__device__ __forceinline__ unsigned pk2(float a, float b) {
    return (unsigned)f2bf(a) | ((unsigned)f2bf(b) << 16);
}

// ---------------- kernel 0: c2[k], s2[k], codes -> permuted MFMA-frag layout ----------------
// codesP[it][kt] is a 1KB region: lane(g*16+c) holds codes[kt*16+c][it*32+g*8 .. +7] bf16.
__global__ __launch_bounds__(256) void k_prep(const float* __restrict__ codes,
                                              const float* __restrict__ scale,
                                              float* __restrict__ c2w,
                                              float* __restrict__ s2w,
                                              unsigned short* __restrict__ codesP) {
    __shared__ float red[KK][8];
    int tid = threadIdx.x;
    int k = tid >> 3, pt = tid & 7;
    int kt = k >> 4, cc = k & 15;
    const float4* p = reinterpret_cast<const float4*>(codes + k * DD + pt * 64);
    float s = 0.f;
#pragma unroll
    for (int i = 0; i < 16; ++i) {
        float4 v = p[i];
        s += v.x * v.x + v.y * v.y + v.z * v.z + v.w * v.w;
        int d0 = pt * 64 + i * 4;
        int it = d0 >> 5, g = (d0 >> 3) & 3;
        uint2 pk = make_uint2(pk2(v.x, v.y), pk2(v.z, v.w));
        ushort4 h = __builtin_bit_cast(ushort4, pk);
        int idx = ((it * 2 + kt) << 9) + (g * 16 + cc) * 8 + (d0 & 7);
        *reinterpret_cast<ushort4*>(codesP + idx) = h;
    }
    red[k][pt] = s;
    __syncthreads();
    if (tid < KK) {
        float c2 = 0.f;
#pragma unroll
        for (int j = 0; j < 8; ++j) c2 += red[tid][j];
        c2w[tid] = c2;
        float sc = scale[tid];
        s2w[tid] = sc * sc;
    }
}

// ---------------- pass A: softmax assignments (deep-pipelined staging) ----------------
// 256 thr (4 waves), 64 tokens/block, grid = 1024. 8 windows of 64 d-rows.
// Hot-loop barriers wait lgkmcnt only -> global prefetches stay in flight across barriers.
__global__ __launch_bounds__(256) void k_assign(const float* __restrict__ x,
                                                const unsigned short* __restrict__ codesP,
                                                const float* __restrict__ c2w,
                                                const float* __restrict__ s2w,
                                                unsigned short* __restrict__ Aout,
                                                float* __restrict__ sAp) {
    __shared__ unsigned short xt[2][64 * 64];   // 2 x 8 KB, swizzled [d64][tok64]
    __shared__ float x2_lds[16][64];
    __shared__ float x2f[64];
    __shared__ float sA_lds[4][32];

    int tid = threadIdx.x;
    int lane = tid & 63;
    int w = tid >> 6;          // wave -> 16 tokens
    int g = lane >> 4, c = lane & 15;
    int bid = blockIdx.x;
    int b = bid >> 6;
    int chunk = bid & 63;
    int tok_base = chunk << 6;

    int srow = tid >> 4;       // 0..15 ; rows srow*4 + i (i 0..3) per window
    int q = tid & 15;          // float4 token-column
    const float* xb = x + (size_t)b * DD * NN + tok_base + q * 4;

    float s2k0 = s2w[c], s2k1 = s2w[c + 16];
    float c2k0 = c2w[c], c2k1 = c2w[c + 16];

    f32x4 acc0 = {}, acc1 = {};
    float x2p[4] = {0.f, 0.f, 0.f, 0.f};
    float4 ld[2][4];

    auto issue = [&](int win, int slot) {
#pragma unroll
        for (int i = 0; i < 4; ++i)
            ld[slot][i] = *reinterpret_cast<const float4*>(
                xb + (size_t)(win * 64 + srow * 4 + i) * NN);
    };
    auto write_tile = [&](int buf, int slot) {
        char* bp = reinterpret_cast<char*>(&xt[buf][0]);
#pragma unroll
        for (int i = 0; i < 4; ++i) {
            float4 v = ld[slot][i];
            x2p[0] += v.x * v.x;
            x2p[1] += v.y * v.y;
            x2p[2] += v.z * v.z;
            x2p[3] += v.w * v.w;
            uint2 pk = make_uint2(pk2(v.x, v.y), pk2(v.z, v.w));
            ushort4 h = __builtin_bit_cast(ushort4, pk);
            int rl = srow * 4 + i;
            int byte = ((rl << 7) + (q << 3)) ^ (((rl >> 3) & 3) << 5);
            *reinterpret_cast<ushort4*>(bp + byte) = h;
        }
    };

    issue(0, 0);
    issue(1, 1);
    write_tile(0, 0);
    asm volatile("s_waitcnt lgkmcnt(0)" ::: "memory");
    __builtin_amdgcn_s_barrier();
    __builtin_amdgcn_sched_barrier(0);

#pragma unroll
    for (int win = 0; win < 8; ++win) {
        if (win <= 5) issue(win + 2, win & 1);
        const char* bp = reinterpret_cast<const char*>(&xt[win & 1][0]);
#pragma unroll
        for (int ksl = 0; ksl < 2; ++ksl) {
            int ks = win * 2 + ksl;
            short8 af;
#pragma unroll
            for (int j = 0; j < 8; ++j) {
                int rl = ksl * 32 + g * 8 + j;
                af[j] = *reinterpret_cast<const short*>(
                    bp + ((((rl << 7) + ((w * 16 + c) << 1)) ^ ((g & 3) << 5))));
            }
            // coalesced permuted codes frags (L2-hot): 16B per lane, wave-linear
            short8 b0 = *reinterpret_cast<const short8*>(codesP + ((ks * 2 + 0) << 9) + lane * 8);
            short8 b1 = *reinterpret_cast<const short8*>(codesP + ((ks * 2 + 1) << 9) + lane * 8);
            acc0 = __builtin_amdgcn_mfma_f32_16x16x32_bf16(af, b0, acc0, 0, 0, 0);
            acc1 = __builtin_amdgcn_mfma_f32_16x16x32_bf16(af, b1, acc1, 0, 0, 0);
        }
        if (win < 7) write_tile((win + 1) & 1, (win + 1) & 1);
        asm volatile("s_waitcnt lgkmcnt(0)" ::: "memory");
        __builtin_amdgcn_s_barrier();
        __builtin_amdgcn_sched_barrier(0);
    }

    // x2 reduce (exact fp32 over raw x)
#pragma unroll
    for (int i = 0; i < 4; ++i) x2_lds[srow][q * 4 + i] = x2p[i];
    __syncthreads();
    if (tid < 64) {
        float ss = 0.f;
#pragma unroll
        for (int j = 0; j < 16; ++j) ss += x2_lds[j][tid];
        x2f[tid] = ss;
    }
    __syncthreads();

    unsigned short* Ab = Aout + (size_t)b * NN * KK;
    float pA0 = 0.f, pA1 = 0.f;
#pragma unroll
    for (int r = 0; r < 4; ++r) {
        int tloc = w * 16 + g * 4 + r;
        float x2r = x2f[tloc];
        float d0v = s2k0 * (x2r - 2.f * acc0[r] + c2k0);
        float d1v = s2k1 * (x2r - 2.f * acc1[r] + c2k1);
        float m = fmaxf(d0v, d1v);
        m = fmaxf(m, __shfl_xor(m, 1));
        m = fmaxf(m, __shfl_xor(m, 2));
        m = fmaxf(m, __shfl_xor(m, 4));
        m = fmaxf(m, __shfl_xor(m, 8));
        float p0 = __expf(d0v - m), p1 = __expf(d1v - m);
        float ss = p0 + p1;
        ss += __shfl_xor(ss, 1);
        ss += __shfl_xor(ss, 2);
        ss += __shfl_xor(ss, 4);
        ss += __shfl_xor(ss, 8);
        float inv = 1.0f / ss;
        float a0 = p0 * inv, a1 = p1 * inv;
        int n = tok_base + tloc;
        unsigned short* pa = Ab + ((size_t)(n >> 3) << 8) + (n & 7);   // [n/8][k=32][n%8]
        pa[c * 8] = f2bf(a0);
        pa[(c + 16) * 8] = f2bf(a1);
        pA0 += a0;
        pA1 += a1;
    }
    pA0 += __shfl_xor(pA0, 16); pA0 += __shfl_xor(pA0, 32);
    pA1 += __shfl_xor(pA1, 16); pA1 += __shfl_xor(pA1, 32);
    if (lane < 16) {
        sA_lds[w][c] = pA0;
        sA_lds[w][c + 16] = pA1;
    }
    __syncthreads();
    if (tid < 32) {
        float ss = sA_lds[0][tid] + sA_lds[1][tid] + sA_lds[2][tid] + sA_lds[3][tid];
        sAp[(b * 64 + chunk) * KK + tid] = ss;
    }
}

// ---------------- pass B: e-partials per (b, 512-tok chunk, 128-d slice) ----------------
// 512 threads (8 waves), no LDS/barriers/atomics; fp32 x, 1 d-row per lane.
__global__ __launch_bounds__(512) void k_agg(const float* __restrict__ x,
                                             const unsigned short* __restrict__ Ain,
                                             float* __restrict__ part) {
    int tid = threadIdx.x;
    int lane = tid & 63;
    int w = tid >> 6;
    int g = lane >> 4, c = lane & 15;
    int bid = blockIdx.x;
    int b = bid >> 5;
    int nc = (bid >> 2) & 7;
    int dh = bid & 3;

    int dr = dh * 128 + w * 16 + c;                       // this lane's d row
    const float* xr = x + ((size_t)b * DD + dr) * NN;
    const unsigned short* Ab = Ain + (size_t)b * NN * KK;

    f32x4 acc0 = {}, acc1 = {};
#pragma unroll 8
    for (int ns = 0; ns < 16; ++ns) {
        int n0 = nc * 512 + ns * 32 + g * 8;
        const unsigned short* pa = Ab + ((size_t)(n0 >> 3) << 8);
        short8 a0 = *reinterpret_cast<const short8*>(pa + c * 8);          // k = c
        short8 a1 = *reinterpret_cast<const short8*>(pa + c * 8 + 128);    // k = c+16
        float4 v0 = *reinterpret_cast<const float4*>(xr + n0);
        float4 v1 = *reinterpret_cast<const float4*>(xr + n0 + 4);
        uint4 pk = make_uint4(pk2(v0.x, v0.y), pk2(v0.z, v0.w),
                              pk2(v1.x, v1.y), pk2(v1.z, v1.w));
        short8 xf = __builtin_bit_cast(short8, pk);
        acc0 = __builtin_amdgcn_mfma_f32_16x16x32_bf16(a0, xf, acc0, 0, 0, 0);
        acc1 = __builtin_amdgcn_mfma_f32_16x16x32_bf16(a1, xf, acc1, 0, 0, 0);
    }
    float* pp = part + (size_t)(b * 8 + nc) * KK * DD;
#pragma unroll
    for (int r = 0; r < 4; ++r) {
        pp[(g * 4 + r) * DD + dr] = acc0[r];
        pp[(16 + g * 4 + r) * DD + dr] = acc1[r];
    }
}

// ---------------- reduce: out = sum_{8 chunks} part - sA*codes ----------------
__global__ __launch_bounds__(256) void k_red(const float* __restrict__ part,
                                             const float* __restrict__ sAp,
                                             const float* __restrict__ codes,
                                             float* __restrict__ out) {
    int bid = blockIdx.x;        // b*32 + k
    int b = bid >> 5, k = bid & 31;
    int tid = threadIdx.x;
    int d = tid * 2;
    float sA = 0.f;
    for (int cc = 0; cc < 64; ++cc) sA += sAp[(b * 64 + cc) * KK + k];   // uniform -> s_loads
    const float* pb = part + (size_t)b * 8 * KK * DD + k * DD + d;
    float s0 = 0.f, s1 = 0.f;
#pragma unroll
    for (int cc = 0; cc < 8; ++cc) {
        float2 v = *reinterpret_cast<const float2*>(pb + (size_t)cc * KK * DD);
        s0 += v.x; s1 += v.y;
    }
    float2 cd = *reinterpret_cast<const float2*>(codes + k * DD + d);
    float2 o;
    o.x = s0 - sA * cd.x;
    o.y = s1 - sA * cd.y;
    *reinterpret_cast<float2*>(out + ((size_t)b * KK + k) * DD + d) = o;
}

extern "C" void kernel_launch(void* const* d_in, const int* in_sizes, int n_in,
                              void* d_out, int out_size, void* d_ws, size_t ws_size,
                              hipStream_t stream) {
    const float* x = (const float*)d_in[0];
    const float* codes = (const float*)d_in[1];
    const float* scale = (const float*)d_in[2];
    float* out = (float*)d_out;
    float* ws = (float*)d_ws;

    float* sAp = ws;                                          // 16*64*32 = 32768 f
    float* c2w = ws + 32768;                                  // 32
    float* s2w = ws + 32800;                                  // 32
    unsigned short* codesP = (unsigned short*)(ws + 32832);   // 32 KB permuted bf16
    unsigned short* Abuf = (unsigned short*)(ws + 41024);     // B*N*K bf16 = 4 MB
    float* part = ws + 41024 + 1048576;                       // 16*8*32*512 f = 8.4 MB

    k_prep<<<1, 256, 0, stream>>>(codes, scale, c2w, s2w, codesP);
    k_assign<<<BB * 64, 256, 0, stream>>>(x, codesP, c2w, s2w, Abuf, sAp);
    k_agg<<<BB * 8 * 4, 512, 0, stream>>>(x, Abuf, part);
    k_red<<<BB * KK, 256, 0, stream>>>(part, sAp, codes, out);
}